// Round 8
// baseline (294.623 us; speedup 1.0000x reference)
//
#include <hip/hip_runtime.h>
#include <hip/hip_bf16.h>
#include <stdint.h>

#define B_ROWS 16384
#define D_IN   512
#define H_DIM  1024
#define K_TOT  1536
#define NKT    48          // K-tiles of 32

typedef __attribute__((ext_vector_type(8)))  short bf16x8;
typedef __attribute__((ext_vector_type(16))) float f32x16;
typedef __attribute__((ext_vector_type(4)))  float float4v;
typedef __attribute__((ext_vector_type(8)))  unsigned short u16x8;

__device__ __forceinline__ unsigned short f2bf(float f) {
    uint32_t u = __float_as_uint(f);
    u = (u + 0x7FFFu + ((u >> 16) & 1u)) >> 16;   // RNE
    return (unsigned short)u;
}

// ---------------------------------------------------------------------------
// Ag in FRAGMENT-LINEAR TILED order (unchanged):
//   granule g = ((bm*48 + tile)*16 + chunk)*64 + lane   (16 B each)
//   lane l, elem j: row = bm*256 + (chunk>>1)*32 + (l&31)
//                   k   = tile*32 + (chunk&1)*16 + (l>>5)*8 + j
// ---------------------------------------------------------------------------
__global__ void cvt_A(const float* __restrict__ x, const float* __restrict__ h,
                      unsigned short* __restrict__ Ag) {
    int t     = blockIdx.x * blockDim.x + threadIdx.x;
    int lane  = t & 63;
    int chunk = (t >> 6) & 15;
    int rest  = t >> 10;            // bm*48 + tile
    int tile  = rest % 48;
    int bm    = rest / 48;
    int row   = bm * 256 + (chunk >> 1) * 32 + (lane & 31);
    int k     = tile * 32 + (chunk & 1) * 16 + (lane >> 5) * 8;
    const float* src = (k < 512) ? (x + (size_t)row * D_IN + k)
                                 : (h + (size_t)row * H_DIM + (k - 512));
    float4v v0 = *(const float4v*)(src);
    float4v v1 = *(const float4v*)(src + 4);
    u16x8 o;
    o[0] = f2bf(v0[0]); o[1] = f2bf(v0[1]); o[2] = f2bf(v0[2]); o[3] = f2bf(v0[3]);
    o[4] = f2bf(v1[0]); o[5] = f2bf(v1[1]); o[6] = f2bf(v1[2]); o[7] = f2bf(v1[3]);
    *(u16x8*)(Ag + (size_t)t * 8) = o;
}

// ---------------------------------------------------------------------------
// Bg fragment-linear tiled, gate-interleaved cols (granularity 32):
//   col c = (h>>5)*128 + gate*32 + (h&31)
// ---------------------------------------------------------------------------
__global__ void cvt_B(const float* __restrict__ Ui, const float* __restrict__ Uf,
                      const float* __restrict__ Uo, const float* __restrict__ Uc,
                      const float* __restrict__ Wi, const float* __restrict__ Wf,
                      const float* __restrict__ Wo, const float* __restrict__ Wc,
                      unsigned short* __restrict__ Bg) {
    int t     = blockIdx.x * blockDim.x + threadIdx.x;
    int lane  = t & 63;
    int chunk = (t >> 6) & 15;
    int rest  = t >> 10;            // bn*48 + tile
    int tile  = rest % 48;
    int bn    = rest / 48;
    int c     = bn * 256 + (chunk >> 1) * 32 + (lane & 31);
    int g     = (c >> 5) & 3;
    int hcol  = ((c >> 7) << 5) | (c & 31);
    int k     = tile * 32 + (chunk & 1) * 16 + (lane >> 5) * 8;
    const float* up = (g == 0) ? Ui : (g == 1) ? Uf : (g == 2) ? Uo : Uc;
    const float* wp = (g == 0) ? Wi : (g == 1) ? Wf : (g == 2) ? Wo : Wc;
    u16x8 o;
    if (k < 512) {
        const float* s = up + (size_t)k * H_DIM + hcol;
        #pragma unroll
        for (int i = 0; i < 8; ++i) o[i] = f2bf(s[(size_t)i * H_DIM]);
    } else {
        const float* s = wp + (size_t)(k - 512) * H_DIM + hcol;
        #pragma unroll
        for (int i = 0; i < 8; ++i) o[i] = f2bf(s[(size_t)i * H_DIM]);
    }
    *(u16x8*)(Bg + (size_t)t * 8) = o;
}

__global__ void cvt_bias(const float* __restrict__ Uib, const float* __restrict__ Ufb,
                         const float* __restrict__ Uob, const float* __restrict__ Ucb,
                         const float* __restrict__ Wib, const float* __restrict__ Wfb,
                         const float* __restrict__ Wob, const float* __restrict__ Wcb,
                         float* __restrict__ bias) {
    int t = blockIdx.x * blockDim.x + threadIdx.x;
    int g = t >> 10, h = t & 1023;
    const float* ub = (g == 0) ? Uib : (g == 1) ? Ufb : (g == 2) ? Uob : Ucb;
    const float* wb = (g == 0) ? Wib : (g == 1) ? Wfb : (g == 2) ? Wob : Wcb;
    bias[t] = ub[h] + wb[h];
}

// ---------------------------------------------------------------------------
// 256x256 GEMM, mfma_f32_32x32x16_bf16. A: GLOBAL->VGPR direct (no LDS),
// software-pipelined 1 tile ahead. B: LDS 5-slot ring (16 KB slots).
// Waves 4M x 2N: wave (wm,wn) owns rows wm*64..+63, cols wn*128..+127.
// Per phase p (per wave): 8 ds_read B(p) ; 4 global_load A(p+1) ;
//   2 glds stage B(p+4) -> slot (p-1)%5 ; 16 MFMA ; vmcnt(8)+barrier.
// Gate: 8 newest vm-ops = {st(p+3):2, A(p+1):4, st(p+4):2} => A(p) and
// st(p+2) retired before the next phase needs them. WAR on slot (p-1)%5:
// its ds_reads completed before phase p-1's MFMA (reg dep) => before stage.
// LDS traffic/phase/CU: 64KB read + 16KB write = 941cy < MFMA 1033cy.
// ---------------------------------------------------------------------------
__global__ __launch_bounds__(512, 2) void lstm_gemm(
        const unsigned short* __restrict__ Ag, const unsigned short* __restrict__ Bg,
        const float* __restrict__ bias, const float* __restrict__ c_old,
        float* __restrict__ out) {
    __shared__ __align__(1024) char lds[81920];   // 5 slots x 16 KiB (B only)

    const int tid = threadIdx.x;
    const int l   = tid & 63;
    const int wv  = tid >> 6;
    const int wm  = wv >> 1;      // 0..3  (64-row slice)
    const int wn  = wv & 1;       // 0..1  (128-col slice)

    // XCD-aware swizzle: per XCD 8bm x 4bn chunks
    const int orig = blockIdx.x;
    const int xcd  = orig & 7;
    const int jj   = orig >> 3;
    const int bn   = (xcd & 3) * 4 + (jj & 3);     // 0..15
    const int bm   = (xcd >> 2) * 32 + (jj >> 2);  // 0..63

    // A per-lane base: frag (mm,ks) of tile t at +t*8192 + (2mm+ks)*512
    const unsigned short* aBase =
        Ag + ((size_t)bm * 48 * 16 + 4 * wm) * 512 + l * 8;
    // B stage source: chunks {2wv, 2wv+1} of tile t
    const unsigned short* bStage =
        Bg + ((size_t)bn * 48 * 16 + 2 * wv) * 512 + l * 8;
    // B read offsets in slot: chunk (wn*8 + nn*2 + ks), byte chunk*1024 + l*16
    const int bRd = wn * 8192 + l * 16;

#define GLDS(SRC, DST) __builtin_amdgcn_global_load_lds(                            \
        (const __attribute__((address_space(1))) void*)(SRC),                       \
        (__attribute__((address_space(3))) void*)(DST), 16, 0, 0)

#define STAGE(T, SLOTOFF) do {                                                      \
    const unsigned short* _s = bStage + (size_t)(T) * 8192;                         \
    char* _d = (char*)lds + (SLOTOFF) + wv * 2048;                                  \
    GLDS(_s, _d);  GLDS(_s + 512, _d + 1024);                                       \
} while (0)

#define ALOAD(AF, T) do {                                                           \
    const unsigned short* _a = aBase + (size_t)(T) * 8192;                          \
    AF[0] = *(const u16x8*)(_a);                                                    \
    AF[1] = *(const u16x8*)(_a + 512);                                              \
    AF[2] = *(const u16x8*)(_a + 1024);                                             \
    AF[3] = *(const u16x8*)(_a + 1536);                                             \
} while (0)

    f32x16 acc[2][4] = {};

#define PHASE(RDOFF, AC, AN, TA, TS, STOFF) do {                                    \
    const char* _B = (const char*)lds + (RDOFF) + bRd;                              \
    bf16x8 bF[4][2];                                                                \
    _Pragma("unroll") for (int nn = 0; nn < 4; ++nn)                                \
        _Pragma("unroll") for (int ks = 0; ks < 2; ++ks)                            \
            bF[nn][ks] = *(const bf16x8*)(_B + (nn * 2 + ks) * 1024);               \
    ALOAD(AN, TA);                                                                  \
    STAGE(TS, STOFF);                                                               \
    __builtin_amdgcn_s_setprio(1);                                                  \
    _Pragma("unroll") for (int ks = 0; ks < 2; ++ks)                                \
        _Pragma("unroll") for (int mm = 0; mm < 2; ++mm)                            \
            _Pragma("unroll") for (int nn = 0; nn < 4; ++nn)                        \
                acc[mm][nn] = __builtin_amdgcn_mfma_f32_32x32x16_bf16(              \
                    (bf16x8)AC[mm * 2 + ks], bF[nn][ks], acc[mm][nn], 0, 0, 0);     \
    __builtin_amdgcn_s_setprio(0);                                                  \
    asm volatile("s_waitcnt vmcnt(8)\ns_barrier" ::: "memory");                     \
} while (0)

    u16x8 a0[4], a1[4];

    // ---- prologue: stage B tiles 0..3 -> slots 0..3; load A(0); gate ----
    STAGE(0, 0); STAGE(1, 16384); STAGE(2, 32768); STAGE(3, 49152);
    ALOAD(a0, 0);
    asm volatile("s_waitcnt vmcnt(8)\ns_barrier" ::: "memory");   // st0,st1 done

    // ring state: phase p reads slot p%5, stages into slot (p+4)%5
    int rdOff = 0;          // p%5 * 16384
    int stOff = 65536;      // (p+4)%5 * 16384

    // ---- main loop: 24 iters x 2 phases = tiles 0..47 ----
    #pragma unroll 1
    for (int i = 0; i < 24; ++i) {
        const int p0 = 2 * i;
        int tA0 = p0 + 1;                                // < 48 always
        int tS0 = p0 + 4;  if (tS0 >= NKT) tS0 -= NKT;   // wrapped: never read
        PHASE(rdOff, a0, a1, tA0, tS0, stOff);
        rdOff = (rdOff == 65536) ? 0 : rdOff + 16384;
        stOff = (stOff == 65536) ? 0 : stOff + 16384;
        int tA1 = p0 + 2;  if (tA1 >= NKT) tA1 -= NKT;   // wrapped: never used
        int tS1 = p0 + 5;  if (tS1 >= NKT) tS1 -= NKT;
        PHASE(rdOff, a1, a0, tA1, tS1, stOff);
        rdOff = (rdOff == 65536) ? 0 : rdOff + 16384;
        stOff = (stOff == 65536) ? 0 : stOff + 16384;
    }
    asm volatile("s_waitcnt vmcnt(0)" ::: "memory");   // drain dummy loads/stages

    // ---- fused LSTM epilogue: gate = nn (in-lane), hh = (bn*2+wn)*32 + col ----
    const int r31 = l & 31;
    const int h5  = l >> 5;
    const int hh  = (bn * 2 + wn) * 32 + r31;
    const float bi  = bias[hh];
    const float bff = bias[1024 + hh];
    const float bo  = bias[2048 + hh];
    const float bc  = bias[3072 + hh];

    #pragma unroll
    for (int mm = 0; mm < 2; ++mm) {
        const int rb = bm * 256 + wm * 64 + mm * 32 + 4 * h5;
        #pragma unroll
        for (int r = 0; r < 16; ++r) {
            const int row = rb + (r & 3) + 8 * (r >> 2);
            float iv = acc[mm][0][r] + bi;
            float fv = acc[mm][1][r] + bff;
            float ov = acc[mm][2][r] + bo;
            float gv = acc[mm][3][r] + bc;
            float it = 1.f / (1.f + __expf(-iv));
            float ft = 1.f / (1.f + __expf(-fv));
            float ot = 1.f / (1.f + __expf(-ov));
            float gt = 1.f - 2.f / (1.f + __expf(2.f * gv));
            float co = c_old[(size_t)row * H_DIM + hh];
            float cn = it * gt + ft * co;
            float th = 1.f - 2.f / (1.f + __expf(2.f * cn));
            out[(size_t)row * H_DIM + hh] = ot * th;                          // h_new
            out[(size_t)B_ROWS * H_DIM + (size_t)row * H_DIM + hh] = cn;      // c
        }
    }
#undef PHASE
#undef ALOAD
#undef STAGE
#undef GLDS
}

extern "C" void kernel_launch(void* const* d_in, const int* in_sizes, int n_in,
                              void* d_out, int out_size, void* d_ws, size_t ws_size,
                              hipStream_t stream) {
    const float* x  = (const float*)d_in[0];
    const float* h0 = (const float*)d_in[1];
    const float* c0 = (const float*)d_in[2];
    const float* Uw[4] = {(const float*)d_in[3],  (const float*)d_in[5],
                          (const float*)d_in[7],  (const float*)d_in[9]};
    const float* Ub[4] = {(const float*)d_in[4],  (const float*)d_in[6],
                          (const float*)d_in[8],  (const float*)d_in[10]};
    const float* Ww[4] = {(const float*)d_in[11], (const float*)d_in[13],
                          (const float*)d_in[15], (const float*)d_in[17]};
    const float* Wb[4] = {(const float*)d_in[12], (const float*)d_in[14],
                          (const float*)d_in[16], (const float*)d_in[18]};

    unsigned short* Ag = (unsigned short*)d_ws;                 // 48 MiB
    unsigned short* Bg = Ag + (size_t)B_ROWS * K_TOT;           // 12 MiB
    float* bias        = (float*)(Bg + (size_t)4096 * K_TOT);   // 16 KiB
    float* out         = (float*)d_out;

    cvt_A<<<12288, 256, 0, stream>>>(x, h0, Ag);
    cvt_B<<<3072, 256, 0, stream>>>(Uw[0], Uw[1], Uw[2], Uw[3],
                                    Ww[0], Ww[1], Ww[2], Ww[3], Bg);
    cvt_bias<<<16, 256, 0, stream>>>(Ub[0], Ub[1], Ub[2], Ub[3],
                                     Wb[0], Wb[1], Wb[2], Wb[3], bias);
    lstm_gemm<<<1024, 512, 0, stream>>>(Ag, Bg, bias, c0, out);
}